// Round 2
// baseline (461.584 us; speedup 1.0000x reference)
//
#include <hip/hip_runtime.h>

// ---------------------------------------------------------------------------
// MetaNet linearized model, MI355X.
//   f0 = xbar @ Wp + bp                      (patch mean is linear)
//   z = f0@W1 + b1 ; f = relu(z) ; base = f@W2 + b2
//   df0 = (c0 (x) xbar)@dWp + sum_t c1 dbp
//   dz  = df0@W1 + (c2 (x) f0)@dW1 + sum_t c3 db1 ; df = mask(z) dz
//   dout= df@W2 + (c4 (x) f)@dW2 + sum_t c5 db2 ; out = base + dout
// GEMM v3: A operand is wave-uniform -> read via SCALAR cache (s_load path,
// v_fmac v,s,v), no LDS in the inner loop (v2 was LDS-return-path-bound:
// 8 ds_read_b128 per 32 fmac = 4x the VALU demand on one shared LDS pipe).
// B stream double-buffered 16-deep so HBM/L3 latency hides under FMAs.
// LDS only for the single-barrier cross-wave reduce; epilogue stores fully
// coalesced. No atomics.
// ---------------------------------------------------------------------------

__global__ void patch_partial_k(const float* __restrict__ x, float* __restrict__ part) {
    int blk = blockIdx.x;            // b*42 + ch*14 + i   (1344 blocks)
    int i  = blk % 14;
    int ch = (blk / 14) % 3;
    int b  = blk / 42;
    int t  = threadIdx.x;            // py*16 + px
    int py = t >> 4, px = t & 15;
    const float* xp = x + (((size_t)(b*3 + ch))*224 + (size_t)(i*16 + py))*224 + px;
    float s = 0.f;
#pragma unroll
    for (int j = 0; j < 14; ++j) s += xp[j*16];
    part[(size_t)blk*256 + t] = s;
}

__global__ void patch_reduce_k(const float* __restrict__ part, float* __restrict__ xbarT) {
    int idx = blockIdx.x*256 + threadIdx.x;   // 24576 = 32*768
    int b = idx / 768;
    int c = idx % 768;
    int ch = c >> 8, t = c & 255;
    const float* p = part + ((size_t)(b*42 + ch*14))*256 + t;
    float s = 0.f;
#pragma unroll
    for (int i = 0; i < 14; ++i) s += p[i*256];
    xbarT[(size_t)c*32 + b] = s * (1.f/196.f);
}

// P[y][col*32+m] = sum_{k in block-tile y} AT[k][m] * B[k][col]
// 256 threads = 4 waves, each wave owns a KW k-quarter of the KB=4*KW tile.
// A read wave-uniform straight from global (scalar pipe); B coalesced,
// 16-deep double-buffered. Cross-wave reduce in padded LDS (stride 34 =
// 2-way bank alias = free), coalesced float4 partial-slice store.
#define LOADB(BUF)                                                   \
    _Pragma("unroll")                                                \
    for (int u = 0; u < 16; ++u) BUF[u] = bp[(size_t)u*N];           \
    bp += (size_t)16*N;

#define FMA_GROUP(BUF, KK)                                           \
    _Pragma("unroll")                                                \
    for (int u = 0; u < 16; ++u) {                                   \
      _Pragma("unroll")                                              \
      for (int m = 0; m < 32; m += 4) {                              \
        float4 a4 = *(const float4*)(ap + ((KK) + u)*32 + m);        \
        acc[m]   += a4.x * BUF[u];                                   \
        acc[m+1] += a4.y * BUF[u];                                   \
        acc[m+2] += a4.z * BUF[u];                                   \
        acc[m+3] += a4.w * BUF[u];                                   \
      }                                                              \
    }

template<int N, int KW>
__global__ __launch_bounds__(256, 4) void gemm4_k(const float* __restrict__ AT,
                                                  const float* __restrict__ Bm,
                                                  float* __restrict__ P) {
    constexpr int KB = 4*KW;
    __shared__ float lds[4*64*34];               // 34816 B, reduce only
    const int tid  = threadIdx.x;
    const int lane = tid & 63;
    // force wave-id into an SGPR so the A pointer is provably uniform
    const int wave = __builtin_amdgcn_readfirstlane(tid >> 6);
    const int col  = blockIdx.x*64 + lane;
    const size_t kblk = (size_t)blockIdx.y * KB;

    const float* ap = AT + (kblk + (size_t)wave*KW)*32;   // uniform
    const float* bp = Bm + (kblk + (size_t)wave*KW)*N + col;

    float acc[32];
#pragma unroll
    for (int m = 0; m < 32; ++m) acc[m] = 0.f;

    float bvA[16], bvB[16];
    LOADB(bvA)
    if constexpr (KW == 16) {
        FMA_GROUP(bvA, 0)
    } else {
#pragma unroll 1
        for (int kk = 0; kk + 32 <= KW; kk += 32) {
            LOADB(bvB)
            FMA_GROUP(bvA, kk)
            if (kk + 32 < KW) { LOADB(bvA) }
            FMA_GROUP(bvB, kk + 16)
        }
    }

    // cross-wave reduce: padded stride 34 floats/col -> 2-way bank alias = free
    {
        float* w0 = lds + (wave*64 + lane)*34;
#pragma unroll
        for (int m = 0; m < 32; m += 2)
            *(float2*)(w0 + m) = make_float2(acc[m], acc[m+1]);
    }
    __syncthreads();
    {
        const int c  = tid >> 2;          // 0..63
        const int mb = (tid & 3) * 8;     // 0,8,16,24 -> wave store is contiguous
        float s[8];
#pragma unroll
        for (int j = 0; j < 8; j += 2) {
            float2 v0 = *(const float2*)(lds + (0*64 + c)*34 + mb + j);
            float2 v1 = *(const float2*)(lds + (1*64 + c)*34 + mb + j);
            float2 v2 = *(const float2*)(lds + (2*64 + c)*34 + mb + j);
            float2 v3 = *(const float2*)(lds + (3*64 + c)*34 + mb + j);
            s[j]   = v0.x + v1.x + v2.x + v3.x;
            s[j+1] = v0.y + v1.y + v2.y + v3.y;
        }
        float* p0 = P + (size_t)blockIdx.y*((size_t)N*32)
                      + ((size_t)blockIdx.x*64 + c)*32 + mb;
        *(float4*)(p0)     = make_float4(s[0], s[1], s[2], s[3]);
        *(float4*)(p0 + 4) = make_float4(s[4], s[5], s[6], s[7]);
    }
}

// out[idx] = bias[idx>>5] + sum_y P[y][idx]
template<int Y>
__global__ void reduce_bias_k(const float* __restrict__ P, const float* __restrict__ bias,
                              float* __restrict__ out, int SZ) {
    int idx = blockIdx.x*256 + threadIdx.x;
    float s = bias[idx >> 5];
#pragma unroll
    for (int y = 0; y < Y; ++y) s += P[(size_t)y*SZ + idx];
    out[idx] = s;
}

// z and f=relu(z) in one pass (SZ=98304)
template<int Y>
__global__ void reduce_zf_k(const float* __restrict__ P, const float* __restrict__ bias,
                            float* __restrict__ zT, float* __restrict__ fT) {
    int idx = blockIdx.x*256 + threadIdx.x;
    float s = bias[idx >> 5];
#pragma unroll
    for (int y = 0; y < Y; ++y) s += P[(size_t)y*98304 + idx];
    zT[idx] = s;
    fT[idx] = fmaxf(s, 0.f);
}

// out = init + sum_y P
template<int Y>
__global__ void reduce_arr_k(const float* __restrict__ P, const float* __restrict__ init,
                             float* __restrict__ out, int SZ) {
    int idx = blockIdx.x*256 + threadIdx.x;
    float s = init[idx];
#pragma unroll
    for (int y = 0; y < Y; ++y) s += P[(size_t)y*SZ + idx];
    out[idx] = s;
}

// dfT = (z>0) ? (init + sum_y P) : 0     (SZ=98304)
template<int Y>
__global__ void reduce_mask_k(const float* __restrict__ P, const float* __restrict__ init,
                              const float* __restrict__ zT, float* __restrict__ dfT) {
    int idx = blockIdx.x*256 + threadIdx.x;
    float s = init[idx];
#pragma unroll 15
    for (int y = 0; y < Y; ++y) s += P[(size_t)y*98304 + idx];
    dfT[idx] = zT[idx] > 0.f ? s : 0.f;
}

// out[b,n] = base + init + sum_y P   (un-transpose on store)
template<int Y>
__global__ void reduce_out_k(const float* __restrict__ P, const float* __restrict__ init,
                             const float* __restrict__ baseT, float* __restrict__ out) {
    int idx = blockIdx.x*256 + threadIdx.x;   // 24576
    float s = init[idx] + baseT[idx];
#pragma unroll 15
    for (int y = 0; y < Y; ++y) s += P[(size_t)y*24576 + idx];
    int n = idx >> 5, b = idx & 31;
    out[b*768 + n] = s;
}

// per-sample MetaNet: coefs[b,48] = relu(base[b]@mW1+mb1)@mW2+mb2
__global__ void metanet_k(const float* __restrict__ baseT, const float* __restrict__ mW1,
                          const float* __restrict__ mb1, const float* __restrict__ mW2,
                          const float* __restrict__ mb2, float* __restrict__ coefs) {
    int b = blockIdx.x;           // 32
    int j = threadIdx.x;          // 256
    __shared__ float xb[768];
    __shared__ float v[192];
    for (int i = j; i < 768; i += 256) xb[i] = baseT[(size_t)i*32 + b];
    __syncthreads();
    if (j < 192) {
        float s0 = 0.f, s1 = 0.f, s2 = 0.f, s3 = 0.f;
#pragma unroll 2
        for (int i = 0; i < 768; i += 4) {
            s0 += xb[i+0] * mW1[(i+0)*192 + j];
            s1 += xb[i+1] * mW1[(i+1)*192 + j];
            s2 += xb[i+2] * mW1[(i+2)*192 + j];
            s3 += xb[i+3] * mW1[(i+3)*192 + j];
        }
        v[j] = fmaxf(mb1[j] + (s0+s1) + (s2+s3), 0.f);
    }
    __syncthreads();
    if (j < 48) {
        float s = mb2[j];
#pragma unroll 8
        for (int i = 0; i < 192; ++i) s += v[i] * mW2[i*48 + j];
        coefs[b*48 + j] = s;
    }
}

// G0T/G1T/G2T (coef-scaled A operands) + delta-bias accumulator inits.
__global__ void build_all_k(const float* __restrict__ coefs, const float* __restrict__ xbarT,
                            const float* __restrict__ f0T, const float* __restrict__ fT,
                            const float* __restrict__ dbp, const float* __restrict__ db1,
                            const float* __restrict__ db2,
                            float* __restrict__ G0T, float* __restrict__ G1T,
                            float* __restrict__ G2T, float* __restrict__ df0b,
                            float* __restrict__ dzb, float* __restrict__ doutb) {
    int idx = blockIdx.x*256 + threadIdx.x;   // 1327104 total
    int b = idx & 31;
    int r = idx >> 5;
    if (r < 6144) {
        int t = r / 768, i = r % 768;
        G0T[idx] = coefs[b*48 + t*6 + 0] * xbarT[(size_t)i*32 + b];
    } else if (r < 12288) {
        int rr = r - 6144;
        int t = rr / 768, i = rr % 768;
        G1T[(size_t)rr*32 + b] = coefs[b*48 + t*6 + 2] * f0T[(size_t)i*32 + b];
    } else if (r < 36864) {
        int rr = r - 12288;
        int t = rr / 3072, i = rr % 3072;
        G2T[(size_t)rr*32 + b] = coefs[b*48 + t*6 + 4] * fT[(size_t)i*32 + b];
    } else if (r < 37632) {
        int n = r - 36864;
        float s = 0.f;
#pragma unroll
        for (int t = 0; t < 8; ++t) s += coefs[b*48 + t*6 + 1] * dbp[t*768 + n];
        df0b[(size_t)n*32 + b] = s;
    } else if (r < 40704) {
        int n = r - 37632;
        float s = 0.f;
#pragma unroll
        for (int t = 0; t < 8; ++t) s += coefs[b*48 + t*6 + 3] * db1[t*3072 + n];
        dzb[(size_t)n*32 + b] = s;
    } else if (r < 41472) {
        int n = r - 40704;
        float s = 0.f;
#pragma unroll
        for (int t = 0; t < 8; ++t) s += coefs[b*48 + t*6 + 5] * db2[t*768 + n];
        doutb[(size_t)n*32 + b] = s;
    }
}

extern "C" void kernel_launch(void* const* d_in, const int* in_sizes, int n_in,
                              void* d_out, int out_size, void* d_ws, size_t ws_size,
                              hipStream_t stream) {
    const float* x   = (const float*)d_in[0];
    const float* Wp  = (const float*)d_in[1];
    const float* bp  = (const float*)d_in[2];
    const float* W1  = (const float*)d_in[3];
    const float* b1  = (const float*)d_in[4];
    const float* W2  = (const float*)d_in[5];
    const float* b2  = (const float*)d_in[6];
    const float* dWp = (const float*)d_in[7];
    const float* dbp = (const float*)d_in[8];
    const float* dW1 = (const float*)d_in[9];
    const float* db1 = (const float*)d_in[10];
    const float* dW2 = (const float*)d_in[11];
    const float* db2 = (const float*)d_in[12];
    const float* mW1 = (const float*)d_in[13];
    const float* mb1 = (const float*)d_in[14];
    const float* mW2 = (const float*)d_in[15];
    const float* mb2 = (const float*)d_in[16];
    float* out = (float*)d_out;

    float* ws    = (float*)d_ws;
    float* part  = ws;                 // 344064
    float* xbarT = part  + 344064;     // 24576   [768,32]
    float* f0T   = xbarT + 24576;      // 24576
    float* zT    = f0T   + 24576;      // 98304
    float* fT    = zT    + 98304;      // 98304
    float* baseT = fT    + 98304;      // 24576
    float* coefs = baseT + 24576;      // 1536
    float* G0T   = coefs + 1536;       // 196608  [6144,32]
    float* G1T   = G0T   + 196608;     // 196608  [6144,32]
    float* G2T   = G1T   + 196608;     // 786432  [24576,32]
    float* df0b  = G2T   + 786432;     // 24576
    float* dzb   = df0b  + 24576;      // 98304
    float* doutb = dzb   + 98304;      // 24576
    float* dfT   = doutb + 24576;      // 98304
    float* df0T  = dfT   + 98304;      // 24576
    // partial arenas (reused across phases; no lifetime overlap)
    float* A1 = df0T + 24576;          // 3145728 : Pz (12), then Pdz (30 slices of 98304)
    float* A2 = A1 + 3145728;          // 3145728 : Pbase(48), then Pdout (120 slices of 24576)
    float* A3 = A2 + 3145728;          // 1179648 : Pf0 (12), then Pdf0 (48 slices of 24576)
    // total ~9.6M floats = ~38.5 MB (unchanged)

    // 1) per-sample patch mean
    patch_partial_k<<<1344, 256, 0, stream>>>(x, part);
    patch_reduce_k<<<96, 256, 0, stream>>>(part, xbarT);

    // 2) base path
    gemm4_k<768, 16><<<dim3(12, 12), 256, 0, stream>>>(xbarT, Wp, A3);   // K=768,  12 slices
    reduce_bias_k<12><<<96, 256, 0, stream>>>(A3, bp, f0T, 24576);
    gemm4_k<3072, 16><<<dim3(48, 12), 256, 0, stream>>>(f0T, W1, A1);    // K=768,  12 slices
    reduce_zf_k<12><<<384, 256, 0, stream>>>(A1, b1, zT, fT);
    gemm4_k<768, 16><<<dim3(12, 48), 256, 0, stream>>>(fT, W2, A2);      // K=3072, 48 slices
    reduce_bias_k<48><<<96, 256, 0, stream>>>(A2, b2, baseT, 24576);

    // 3) MetaNet coefficients
    metanet_k<<<32, 256, 0, stream>>>(baseT, mW1, mb1, mW2, mb2, coefs);

    // 4) scaled A-operands + delta-bias inits
    build_all_k<<<5184, 256, 0, stream>>>(coefs, xbarT, f0T, fT, dbp, db1, db2,
                                          G0T, G1T, G2T, df0b, dzb, doutb);

    // 5) JVP chain
    gemm4_k<768, 32><<<dim3(12, 48), 256, 0, stream>>>(G0T, dWp, A3);    // K=6144, 48 slices
    reduce_arr_k<48><<<96, 256, 0, stream>>>(A3, df0b, df0T, 24576);
    gemm4_k<3072, 32><<<dim3(48, 6), 256, 0, stream>>>(df0T, W1, A1);    // K=768, slices 0..6
    gemm4_k<3072, 64><<<dim3(48, 24), 256, 0, stream>>>(G1T, dW1, A1 + (size_t)6*98304);  // K=6144, slices 6..30
    reduce_mask_k<30><<<384, 256, 0, stream>>>(A1, dzb, zT, dfT);
    gemm4_k<768, 32><<<dim3(12, 24), 256, 0, stream>>>(dfT, W2, A2);     // K=3072, slices 0..24
    gemm4_k<768, 64><<<dim3(12, 96), 256, 0, stream>>>(G2T, dW2, A2 + (size_t)24*24576); // K=24576, slices 24..120
    reduce_out_k<120><<<96, 256, 0, stream>>>(A2, doutb, baseT, out);
}

// Round 3
// 379.024 us; speedup vs baseline: 1.2178x; 1.2178x over previous
//
#include <hip/hip_runtime.h>

// ---------------------------------------------------------------------------
// MetaNet linearized model, MI355X.
//   f0 = xbar @ Wp + bp                      (patch mean is linear)
//   z = f0@W1 + b1 ; f = relu(z) ; base = f@W2 + b2
//   df0 = (c0 (x) xbar)@dWp + sum_t c1 dbp
//   dz  = df0@W1 + (c2 (x) f0)@dW1 + sum_t c3 db1 ; df = mask(z) dz
//   dout= df@W2 + (c4 (x) f)@dW2 + sum_t c5 db2 ; out = base + dout
// GEMM v4: the v1/v2/v3 plateau (75us) was A-operand waits draining the
// B prefetch (vmcnt/lgkmcnt are oldest-first: waiting on a just-issued A
// load drains the 16 B loads in flight). Fix: A-tile staged in LDS, then
// REGISTER double-buffered per k (8 uniform ds_read_b128 for k+1 issued
// before 32 fmacs on resident k). DS is in-order -> precise lgkmcnt(8);
// B batches issued only at 16-k boundaries -> never drained. No atomics.
// ---------------------------------------------------------------------------

__global__ void patch_partial_k(const float* __restrict__ x, float* __restrict__ part) {
    int blk = blockIdx.x;            // b*42 + ch*14 + i   (1344 blocks)
    int i  = blk % 14;
    int ch = (blk / 14) % 3;
    int b  = blk / 42;
    int t  = threadIdx.x;            // py*16 + px
    int py = t >> 4, px = t & 15;
    const float* xp = x + (((size_t)(b*3 + ch))*224 + (size_t)(i*16 + py))*224 + px;
    float s = 0.f;
#pragma unroll
    for (int j = 0; j < 14; ++j) s += xp[j*16];
    part[(size_t)blk*256 + t] = s;
}

__global__ void patch_reduce_k(const float* __restrict__ part, float* __restrict__ xbarT) {
    int idx = blockIdx.x*256 + threadIdx.x;   // 24576 = 32*768
    int b = idx / 768;
    int c = idx % 768;
    int ch = c >> 8, t = c & 255;
    const float* p = part + ((size_t)(b*42 + ch*14))*256 + t;
    float s = 0.f;
#pragma unroll
    for (int i = 0; i < 14; ++i) s += p[i*256];
    xbarT[(size_t)c*32 + b] = s * (1.f/196.f);
}

// P[y][col*32+m] = sum_{k in block-tile y} AT[k][m] * B[k][col]
// 256 threads = 4 waves, each wave owns a KW k-quarter of the KB=4*KW tile.
// A-tile in LDS; per-k register double-buffer a0/a1 (8 uniform ds_read_b128
// issued one k ahead). B coalesced dword stream, 16-deep double-buffered,
// issued only at 16-k boundaries. Cross-wave reduce in padded LDS, coalesced
// float4 partial store.
#define LOADB(BUF)                                                   \
    _Pragma("unroll")                                                \
    for (int u = 0; u < 16; ++u) BUF[u] = bp[(size_t)u*N];           \
    bp += (size_t)16*N;

#define FMAC8(AR, BV)                                                \
    _Pragma("unroll")                                                \
    for (int m = 0; m < 8; ++m) {                                    \
        acc[4*m]   += AR[m].x * (BV);                                \
        acc[4*m+1] += AR[m].y * (BV);                                \
        acc[4*m+2] += AR[m].z * (BV);                                \
        acc[4*m+3] += AR[m].w * (BV);                                \
    }

#define PREF(AR, KIDX)                                               \
    _Pragma("unroll")                                                \
    for (int r = 0; r < 8; ++r)                                      \
        AR[r] = *(const float4*)(As + (KIDX)*32 + r*4);

// 16 k-steps: prefetch k+1 while fmac'ing k (even/odd static buffers).
#define HALF(BUF, KK)                                                \
    _Pragma("unroll")                                                \
    for (int u = 0; u < 16; u += 2) {                                \
        PREF(a1, (KK)+u+1)                                           \
        FMAC8(a0, BUF[u])                                            \
        PREF(a0, (KK)+u+2)                                           \
        FMAC8(a1, BUF[u+1])                                          \
    }

template<int N, int KW>
__global__ __launch_bounds__(256, 3) void gemm4_k(const float* __restrict__ AT,
                                                  const float* __restrict__ Bm,
                                                  float* __restrict__ P) {
    constexpr int KB = 4*KW;
    __shared__ float lds[8704];                  // A-tile (<=8192) / reduce (8704), time-shared
    const int tid  = threadIdx.x;
    const int lane = tid & 63;
    const int wave = __builtin_amdgcn_readfirstlane(tid >> 6);
    const int col  = blockIdx.x*64 + lane;
    const size_t kblk = (size_t)blockIdx.y * KB;

    // stage A tile (coalesced float4), overlapping with first B batch issue
    {
        const float4* Ag = (const float4*)(AT + kblk*32);
        float4* As4 = (float4*)lds;
#pragma unroll
        for (int i = 0; i < KB*32/4/256; ++i)
            As4[i*256 + tid] = Ag[i*256 + tid];
    }

    const float* bp = Bm + (kblk + (size_t)wave*KW)*N + col;
    float bvA[16], bvB[16];
    LOADB(bvA)                                   // independent of LDS; overlaps barrier

    __syncthreads();
    const float* As = lds + wave*KW*32;          // uniform per wave

    float acc[32];
#pragma unroll
    for (int m = 0; m < 32; ++m) acc[m] = 0.f;

    float4 a0[8], a1[8];
    PREF(a0, 0)

    if constexpr (KW == 16) {
        HALF(bvA, 0)
    } else {
#pragma unroll 1
        for (int kk = 0; kk + 32 <= KW; kk += 32) {
            LOADB(bvB)
            HALF(bvA, kk)
            if (kk + 32 < KW) { LOADB(bvA) }
            HALF(bvB, kk + 16)
        }
    }

    // reduce region overlaps A-tile region -> barrier before overwriting
    __syncthreads();
    {
        float* w0 = lds + (wave*64 + lane)*34;   // stride 34: 2-way bank alias = free
#pragma unroll
        for (int m = 0; m < 32; m += 2)
            *(float2*)(w0 + m) = make_float2(acc[m], acc[m+1]);
    }
    __syncthreads();
    {
        const int c  = tid >> 2;          // 0..63
        const int mb = (tid & 3) * 8;     // wave store is contiguous
        float s[8];
#pragma unroll
        for (int j = 0; j < 8; j += 2) {
            float2 v0 = *(const float2*)(lds + (0*64 + c)*34 + mb + j);
            float2 v1 = *(const float2*)(lds + (1*64 + c)*34 + mb + j);
            float2 v2 = *(const float2*)(lds + (2*64 + c)*34 + mb + j);
            float2 v3 = *(const float2*)(lds + (3*64 + c)*34 + mb + j);
            s[j]   = v0.x + v1.x + v2.x + v3.x;
            s[j+1] = v0.y + v1.y + v2.y + v3.y;
        }
        float* p0 = P + (size_t)blockIdx.y*((size_t)N*32)
                      + ((size_t)blockIdx.x*64 + c)*32 + mb;
        *(float4*)(p0)     = make_float4(s[0], s[1], s[2], s[3]);
        *(float4*)(p0 + 4) = make_float4(s[4], s[5], s[6], s[7]);
    }
}

// out[idx] = bias[idx>>5] + sum_y P[y][idx]
template<int Y>
__global__ void reduce_bias_k(const float* __restrict__ P, const float* __restrict__ bias,
                              float* __restrict__ out, int SZ) {
    int idx = blockIdx.x*256 + threadIdx.x;
    float s = bias[idx >> 5];
#pragma unroll
    for (int y = 0; y < Y; ++y) s += P[(size_t)y*SZ + idx];
    out[idx] = s;
}

// z and f=relu(z) in one pass (SZ=98304)
template<int Y>
__global__ void reduce_zf_k(const float* __restrict__ P, const float* __restrict__ bias,
                            float* __restrict__ zT, float* __restrict__ fT) {
    int idx = blockIdx.x*256 + threadIdx.x;
    float s = bias[idx >> 5];
#pragma unroll
    for (int y = 0; y < Y; ++y) s += P[(size_t)y*98304 + idx];
    zT[idx] = s;
    fT[idx] = fmaxf(s, 0.f);
}

// out = init + sum_y P
template<int Y>
__global__ void reduce_arr_k(const float* __restrict__ P, const float* __restrict__ init,
                             float* __restrict__ out, int SZ) {
    int idx = blockIdx.x*256 + threadIdx.x;
    float s = init[idx];
#pragma unroll
    for (int y = 0; y < Y; ++y) s += P[(size_t)y*SZ + idx];
    out[idx] = s;
}

// dfT = (z>0) ? (init + sum_y P) : 0     (SZ=98304)
template<int Y>
__global__ void reduce_mask_k(const float* __restrict__ P, const float* __restrict__ init,
                              const float* __restrict__ zT, float* __restrict__ dfT) {
    int idx = blockIdx.x*256 + threadIdx.x;
    float s = init[idx];
#pragma unroll 15
    for (int y = 0; y < Y; ++y) s += P[(size_t)y*98304 + idx];
    dfT[idx] = zT[idx] > 0.f ? s : 0.f;
}

// out[b,n] = base + init + sum_y P   (un-transpose on store)
template<int Y>
__global__ void reduce_out_k(const float* __restrict__ P, const float* __restrict__ init,
                             const float* __restrict__ baseT, float* __restrict__ out) {
    int idx = blockIdx.x*256 + threadIdx.x;   // 24576
    float s = init[idx] + baseT[idx];
#pragma unroll 15
    for (int y = 0; y < Y; ++y) s += P[(size_t)y*24576 + idx];
    int n = idx >> 5, b = idx & 31;
    out[b*768 + n] = s;
}

// per-sample MetaNet: coefs[b,48] = relu(base[b]@mW1+mb1)@mW2+mb2
__global__ void metanet_k(const float* __restrict__ baseT, const float* __restrict__ mW1,
                          const float* __restrict__ mb1, const float* __restrict__ mW2,
                          const float* __restrict__ mb2, float* __restrict__ coefs) {
    int b = blockIdx.x;           // 32
    int j = threadIdx.x;          // 256
    __shared__ float xb[768];
    __shared__ float v[192];
    for (int i = j; i < 768; i += 256) xb[i] = baseT[(size_t)i*32 + b];
    __syncthreads();
    if (j < 192) {
        float s0 = 0.f, s1 = 0.f, s2 = 0.f, s3 = 0.f;
#pragma unroll 2
        for (int i = 0; i < 768; i += 4) {
            s0 += xb[i+0] * mW1[(i+0)*192 + j];
            s1 += xb[i+1] * mW1[(i+1)*192 + j];
            s2 += xb[i+2] * mW1[(i+2)*192 + j];
            s3 += xb[i+3] * mW1[(i+3)*192 + j];
        }
        v[j] = fmaxf(mb1[j] + (s0+s1) + (s2+s3), 0.f);
    }
    __syncthreads();
    if (j < 48) {
        float s = mb2[j];
#pragma unroll 8
        for (int i = 0; i < 192; ++i) s += v[i] * mW2[i*48 + j];
        coefs[b*48 + j] = s;
    }
}

// G0T/G1T/G2T (coef-scaled A operands) + delta-bias accumulator inits.
__global__ void build_all_k(const float* __restrict__ coefs, const float* __restrict__ xbarT,
                            const float* __restrict__ f0T, const float* __restrict__ fT,
                            const float* __restrict__ dbp, const float* __restrict__ db1,
                            const float* __restrict__ db2,
                            float* __restrict__ G0T, float* __restrict__ G1T,
                            float* __restrict__ G2T, float* __restrict__ df0b,
                            float* __restrict__ dzb, float* __restrict__ doutb) {
    int idx = blockIdx.x*256 + threadIdx.x;   // 1327104 total
    int b = idx & 31;
    int r = idx >> 5;
    if (r < 6144) {
        int t = r / 768, i = r % 768;
        G0T[idx] = coefs[b*48 + t*6 + 0] * xbarT[(size_t)i*32 + b];
    } else if (r < 12288) {
        int rr = r - 6144;
        int t = rr / 768, i = rr % 768;
        G1T[(size_t)rr*32 + b] = coefs[b*48 + t*6 + 2] * f0T[(size_t)i*32 + b];
    } else if (r < 36864) {
        int rr = r - 12288;
        int t = rr / 3072, i = rr % 3072;
        G2T[(size_t)rr*32 + b] = coefs[b*48 + t*6 + 4] * fT[(size_t)i*32 + b];
    } else if (r < 37632) {
        int n = r - 36864;
        float s = 0.f;
#pragma unroll
        for (int t = 0; t < 8; ++t) s += coefs[b*48 + t*6 + 1] * dbp[t*768 + n];
        df0b[(size_t)n*32 + b] = s;
    } else if (r < 40704) {
        int n = r - 37632;
        float s = 0.f;
#pragma unroll
        for (int t = 0; t < 8; ++t) s += coefs[b*48 + t*6 + 3] * db1[t*3072 + n];
        dzb[(size_t)n*32 + b] = s;
    } else if (r < 41472) {
        int n = r - 40704;
        float s = 0.f;
#pragma unroll
        for (int t = 0; t < 8; ++t) s += coefs[b*48 + t*6 + 5] * db2[t*768 + n];
        doutb[(size_t)n*32 + b] = s;
    }
}

extern "C" void kernel_launch(void* const* d_in, const int* in_sizes, int n_in,
                              void* d_out, int out_size, void* d_ws, size_t ws_size,
                              hipStream_t stream) {
    const float* x   = (const float*)d_in[0];
    const float* Wp  = (const float*)d_in[1];
    const float* bp  = (const float*)d_in[2];
    const float* W1  = (const float*)d_in[3];
    const float* b1  = (const float*)d_in[4];
    const float* W2  = (const float*)d_in[5];
    const float* b2  = (const float*)d_in[6];
    const float* dWp = (const float*)d_in[7];
    const float* dbp = (const float*)d_in[8];
    const float* dW1 = (const float*)d_in[9];
    const float* db1 = (const float*)d_in[10];
    const float* dW2 = (const float*)d_in[11];
    const float* db2 = (const float*)d_in[12];
    const float* mW1 = (const float*)d_in[13];
    const float* mb1 = (const float*)d_in[14];
    const float* mW2 = (const float*)d_in[15];
    const float* mb2 = (const float*)d_in[16];
    float* out = (float*)d_out;

    float* ws    = (float*)d_ws;
    float* part  = ws;                 // 344064
    float* xbarT = part  + 344064;     // 24576   [768,32]
    float* f0T   = xbarT + 24576;      // 24576
    float* zT    = f0T   + 24576;      // 98304
    float* fT    = zT    + 98304;      // 98304
    float* baseT = fT    + 98304;      // 24576
    float* coefs = baseT + 24576;      // 1536
    float* G0T   = coefs + 1536;       // 196608  [6144,32]
    float* G1T   = G0T   + 196608;     // 196608  [6144,32]
    float* G2T   = G1T   + 196608;     // 786432  [24576,32]
    float* df0b  = G2T   + 786432;     // 24576
    float* dzb   = df0b  + 24576;      // 98304
    float* doutb = dzb   + 98304;      // 24576
    float* dfT   = doutb + 24576;      // 98304
    float* df0T  = dfT   + 98304;      // 24576
    // partial arenas (reused across phases; no lifetime overlap)
    float* A1 = df0T + 24576;          // 3145728 : Pz (12), then Pdz (30 slices of 98304)
    float* A2 = A1 + 3145728;          // 3145728 : Pbase(48), then Pdout (120 slices of 24576)
    float* A3 = A2 + 3145728;          // 1179648 : Pf0 (12), then Pdf0 (48 slices of 24576)
    // total ~9.6M floats = ~38.5 MB (unchanged)

    // 1) per-sample patch mean
    patch_partial_k<<<1344, 256, 0, stream>>>(x, part);
    patch_reduce_k<<<96, 256, 0, stream>>>(part, xbarT);

    // 2) base path
    gemm4_k<768, 16><<<dim3(12, 12), 256, 0, stream>>>(xbarT, Wp, A3);   // K=768,  12 slices
    reduce_bias_k<12><<<96, 256, 0, stream>>>(A3, bp, f0T, 24576);
    gemm4_k<3072, 16><<<dim3(48, 12), 256, 0, stream>>>(f0T, W1, A1);    // K=768,  12 slices
    reduce_zf_k<12><<<384, 256, 0, stream>>>(A1, b1, zT, fT);
    gemm4_k<768, 16><<<dim3(12, 48), 256, 0, stream>>>(fT, W2, A2);      // K=3072, 48 slices
    reduce_bias_k<48><<<96, 256, 0, stream>>>(A2, b2, baseT, 24576);

    // 3) MetaNet coefficients
    metanet_k<<<32, 256, 0, stream>>>(baseT, mW1, mb1, mW2, mb2, coefs);

    // 4) scaled A-operands + delta-bias inits
    build_all_k<<<5184, 256, 0, stream>>>(coefs, xbarT, f0T, fT, dbp, db1, db2,
                                          G0T, G1T, G2T, df0b, dzb, doutb);

    // 5) JVP chain
    gemm4_k<768, 32><<<dim3(12, 48), 256, 0, stream>>>(G0T, dWp, A3);    // K=6144, 48 slices
    reduce_arr_k<48><<<96, 256, 0, stream>>>(A3, df0b, df0T, 24576);
    gemm4_k<3072, 32><<<dim3(48, 6), 256, 0, stream>>>(df0T, W1, A1);    // K=768, slices 0..6
    gemm4_k<3072, 64><<<dim3(48, 24), 256, 0, stream>>>(G1T, dW1, A1 + (size_t)6*98304);  // K=6144, slices 6..30
    reduce_mask_k<30><<<384, 256, 0, stream>>>(A1, dzb, zT, dfT);
    gemm4_k<768, 32><<<dim3(12, 24), 256, 0, stream>>>(dfT, W2, A2);     // K=3072, slices 0..24
    gemm4_k<768, 64><<<dim3(12, 96), 256, 0, stream>>>(G2T, dW2, A2 + (size_t)24*24576); // K=24576, slices 24..120
    reduce_out_k<120><<<96, 256, 0, stream>>>(A2, doutb, baseT, out);
}

// Round 4
// 337.114 us; speedup vs baseline: 1.3692x; 1.1243x over previous
//
#include <hip/hip_runtime.h>

// ---------------------------------------------------------------------------
// MetaNet linearized model, MI355X.
//   f0 = xbar @ Wp + bp                      (patch mean is linear)
//   z = f0@W1 + b1 ; f = relu(z) ; base = f@W2 + b2
//   df0 = (c0 (x) xbar)@dWp + sum_t c1 dbp
//   dz  = df0@W1 + (c2 (x) f0)@dW1 + sum_t c3 db1 ; df = mask(z) dz
//   dout= df@W2 + (c4 (x) f)@dW2 + sum_t c5 db2 ; out = base + dout
// GEMM v4 (kept): A-tile in LDS + per-k register double-buffer, B 16-deep
// double-buffered at 16-k boundaries only -> prefetch never drained.
// v5: MetaNet was a 58us latency-bound tail (32 blocks, serial 768-dots,
// VALUBusy 0.3%). Split into metanet1_k (192 blocks, 8-way k-split + LDS
// reduce) + metanet2_k (4-way k-split): ~5us total. No atomics anywhere.
// ---------------------------------------------------------------------------

__global__ void patch_partial_k(const float* __restrict__ x, float* __restrict__ part) {
    int blk = blockIdx.x;            // b*42 + ch*14 + i   (1344 blocks)
    int i  = blk % 14;
    int ch = (blk / 14) % 3;
    int b  = blk / 42;
    int t  = threadIdx.x;            // py*16 + px
    int py = t >> 4, px = t & 15;
    const float* xp = x + (((size_t)(b*3 + ch))*224 + (size_t)(i*16 + py))*224 + px;
    float s = 0.f;
#pragma unroll
    for (int j = 0; j < 14; ++j) s += xp[j*16];
    part[(size_t)blk*256 + t] = s;
}

__global__ void patch_reduce_k(const float* __restrict__ part, float* __restrict__ xbarT) {
    int idx = blockIdx.x*256 + threadIdx.x;   // 24576 = 32*768
    int b = idx / 768;
    int c = idx % 768;
    int ch = c >> 8, t = c & 255;
    const float* p = part + ((size_t)(b*42 + ch*14))*256 + t;
    float s = 0.f;
#pragma unroll
    for (int i = 0; i < 14; ++i) s += p[i*256];
    xbarT[(size_t)c*32 + b] = s * (1.f/196.f);
}

// P[y][col*32+m] = sum_{k in block-tile y} AT[k][m] * B[k][col]
// 256 threads = 4 waves, each wave owns a KW k-quarter of the KB=4*KW tile.
// A-tile in LDS; per-k register double-buffer a0/a1 (8 uniform ds_read_b128
// issued one k ahead). B coalesced dword stream, 16-deep double-buffered,
// issued only at 16-k boundaries. Cross-wave reduce in padded LDS, coalesced
// float4 partial store.
#define LOADB(BUF)                                                   \
    _Pragma("unroll")                                                \
    for (int u = 0; u < 16; ++u) BUF[u] = bp[(size_t)u*N];           \
    bp += (size_t)16*N;

#define FMAC8(AR, BV)                                                \
    _Pragma("unroll")                                                \
    for (int m = 0; m < 8; ++m) {                                    \
        acc[4*m]   += AR[m].x * (BV);                                \
        acc[4*m+1] += AR[m].y * (BV);                                \
        acc[4*m+2] += AR[m].z * (BV);                                \
        acc[4*m+3] += AR[m].w * (BV);                                \
    }

#define PREF(AR, KIDX)                                               \
    _Pragma("unroll")                                                \
    for (int r = 0; r < 8; ++r)                                      \
        AR[r] = *(const float4*)(As + (KIDX)*32 + r*4);

// 16 k-steps: prefetch k+1 while fmac'ing k (even/odd static buffers).
#define HALF(BUF, KK)                                                \
    _Pragma("unroll")                                                \
    for (int u = 0; u < 16; u += 2) {                                \
        PREF(a1, (KK)+u+1)                                           \
        FMAC8(a0, BUF[u])                                            \
        PREF(a0, (KK)+u+2)                                           \
        FMAC8(a1, BUF[u+1])                                          \
    }

template<int N, int KW>
__global__ __launch_bounds__(256, 3) void gemm4_k(const float* __restrict__ AT,
                                                  const float* __restrict__ Bm,
                                                  float* __restrict__ P) {
    constexpr int KB = 4*KW;
    __shared__ float lds[8704];                  // A-tile (<=8192) / reduce (8704), time-shared
    const int tid  = threadIdx.x;
    const int lane = tid & 63;
    const int wave = __builtin_amdgcn_readfirstlane(tid >> 6);
    const int col  = blockIdx.x*64 + lane;
    const size_t kblk = (size_t)blockIdx.y * KB;

    // stage A tile (coalesced float4), overlapping with first B batch issue
    {
        const float4* Ag = (const float4*)(AT + kblk*32);
        float4* As4 = (float4*)lds;
#pragma unroll
        for (int i = 0; i < KB*32/4/256; ++i)
            As4[i*256 + tid] = Ag[i*256 + tid];
    }

    const float* bp = Bm + (kblk + (size_t)wave*KW)*N + col;
    float bvA[16], bvB[16];
    LOADB(bvA)                                   // independent of LDS; overlaps barrier

    __syncthreads();
    const float* As = lds + wave*KW*32;          // uniform per wave

    float acc[32];
#pragma unroll
    for (int m = 0; m < 32; ++m) acc[m] = 0.f;

    float4 a0[8], a1[8];
    PREF(a0, 0)

    if constexpr (KW == 16) {
        HALF(bvA, 0)
    } else {
#pragma unroll 1
        for (int kk = 0; kk + 32 <= KW; kk += 32) {
            LOADB(bvB)
            HALF(bvA, kk)
            if (kk + 32 < KW) { LOADB(bvA) }
            HALF(bvB, kk + 16)
        }
    }

    // reduce region overlaps A-tile region -> barrier before overwriting
    __syncthreads();
    {
        float* w0 = lds + (wave*64 + lane)*34;   // stride 34: 2-way bank alias = free
#pragma unroll
        for (int m = 0; m < 32; m += 2)
            *(float2*)(w0 + m) = make_float2(acc[m], acc[m+1]);
    }
    __syncthreads();
    {
        const int c  = tid >> 2;          // 0..63
        const int mb = (tid & 3) * 8;     // wave store is contiguous
        float s[8];
#pragma unroll
        for (int j = 0; j < 8; j += 2) {
            float2 v0 = *(const float2*)(lds + (0*64 + c)*34 + mb + j);
            float2 v1 = *(const float2*)(lds + (1*64 + c)*34 + mb + j);
            float2 v2 = *(const float2*)(lds + (2*64 + c)*34 + mb + j);
            float2 v3 = *(const float2*)(lds + (3*64 + c)*34 + mb + j);
            s[j]   = v0.x + v1.x + v2.x + v3.x;
            s[j+1] = v0.y + v1.y + v2.y + v3.y;
        }
        float* p0 = P + (size_t)blockIdx.y*((size_t)N*32)
                      + ((size_t)blockIdx.x*64 + c)*32 + mb;
        *(float4*)(p0)     = make_float4(s[0], s[1], s[2], s[3]);
        *(float4*)(p0 + 4) = make_float4(s[4], s[5], s[6], s[7]);
    }
}

// out[idx] = bias[idx>>5] + sum_y P[y][idx]
template<int Y>
__global__ void reduce_bias_k(const float* __restrict__ P, const float* __restrict__ bias,
                              float* __restrict__ out, int SZ) {
    int idx = blockIdx.x*256 + threadIdx.x;
    float s = bias[idx >> 5];
#pragma unroll
    for (int y = 0; y < Y; ++y) s += P[(size_t)y*SZ + idx];
    out[idx] = s;
}

// z and f=relu(z) in one pass (SZ=98304)
template<int Y>
__global__ void reduce_zf_k(const float* __restrict__ P, const float* __restrict__ bias,
                            float* __restrict__ zT, float* __restrict__ fT) {
    int idx = blockIdx.x*256 + threadIdx.x;
    float s = bias[idx >> 5];
#pragma unroll
    for (int y = 0; y < Y; ++y) s += P[(size_t)y*98304 + idx];
    zT[idx] = s;
    fT[idx] = fmaxf(s, 0.f);
}

// out = init + sum_y P
template<int Y>
__global__ void reduce_arr_k(const float* __restrict__ P, const float* __restrict__ init,
                             float* __restrict__ out, int SZ) {
    int idx = blockIdx.x*256 + threadIdx.x;
    float s = init[idx];
#pragma unroll
    for (int y = 0; y < Y; ++y) s += P[(size_t)y*SZ + idx];
    out[idx] = s;
}

// dfT = (z>0) ? (init + sum_y P) : 0     (SZ=98304)
template<int Y>
__global__ void reduce_mask_k(const float* __restrict__ P, const float* __restrict__ init,
                              const float* __restrict__ zT, float* __restrict__ dfT) {
    int idx = blockIdx.x*256 + threadIdx.x;
    float s = init[idx];
#pragma unroll 15
    for (int y = 0; y < Y; ++y) s += P[(size_t)y*98304 + idx];
    dfT[idx] = zT[idx] > 0.f ? s : 0.f;
}

// out[b,n] = base + init + sum_y P   (un-transpose on store)
template<int Y>
__global__ void reduce_out_k(const float* __restrict__ P, const float* __restrict__ init,
                             const float* __restrict__ baseT, float* __restrict__ out) {
    int idx = blockIdx.x*256 + threadIdx.x;   // 24576
    float s = init[idx] + baseT[idx];
#pragma unroll 15
    for (int y = 0; y < Y; ++y) s += P[(size_t)y*24576 + idx];
    int n = idx >> 5, b = idx & 31;
    out[b*768 + n] = s;
}

// MetaNet layer 1: v[b,j] = relu(mb1[j] + sum_i base[b,i]*mW1[i,j])
// grid (32 b, 6 jg), 256 thr: 32 j's per block, 8-way k-split per j.
__global__ void metanet1_k(const float* __restrict__ baseT, const float* __restrict__ mW1,
                           const float* __restrict__ mb1, float* __restrict__ v) {
    int b  = blockIdx.x;
    int jg = blockIdx.y;
    int jj = threadIdx.x & 31;
    int ks = threadIdx.x >> 5;              // 0..7
    int j  = jg*32 + jj;
    const float* wp = mW1 + (size_t)(ks*96)*192 + j;   // coalesced 128B/segment
    const float* xp = baseT + (size_t)(ks*96)*32 + b;  // same-addr broadcast
    float s = 0.f;
#pragma unroll 8
    for (int i = 0; i < 96; ++i) s += xp[i*32] * wp[i*192];
    __shared__ float red[256];
    red[threadIdx.x] = s;
    __syncthreads();
    if (threadIdx.x < 32) {
        float t = mb1[j];
#pragma unroll
        for (int k = 0; k < 8; ++k) t += red[k*32 + threadIdx.x];
        v[b*192 + jg*32 + threadIdx.x] = fmaxf(t, 0.f);
    }
}

// MetaNet layer 2: coefs[b,o] = mb2[o] + sum_i v[b,i]*mW2[i,o]
// grid 32, 256 thr: 48 outputs, 4-way k-split.
__global__ void metanet2_k(const float* __restrict__ v, const float* __restrict__ mW2,
                           const float* __restrict__ mb2, float* __restrict__ coefs) {
    int b  = blockIdx.x;
    int o  = threadIdx.x & 63;
    int ks = threadIdx.x >> 6;              // 0..3
    float s = 0.f;
    if (o < 48) {
        const float* vp = v + b*192 + ks*48;
        const float* wp = mW2 + (size_t)(ks*48)*48 + o;
#pragma unroll 8
        for (int i = 0; i < 48; ++i) s += vp[i] * wp[i*48];
    }
    __shared__ float red[256];
    red[threadIdx.x] = s;
    __syncthreads();
    if (threadIdx.x < 48) {
        float t = mb2[threadIdx.x];
#pragma unroll
        for (int k = 0; k < 4; ++k) t += red[k*64 + threadIdx.x];
        coefs[b*48 + threadIdx.x] = t;
    }
}

// G0T/G1T/G2T (coef-scaled A operands) + delta-bias accumulator inits.
__global__ void build_all_k(const float* __restrict__ coefs, const float* __restrict__ xbarT,
                            const float* __restrict__ f0T, const float* __restrict__ fT,
                            const float* __restrict__ dbp, const float* __restrict__ db1,
                            const float* __restrict__ db2,
                            float* __restrict__ G0T, float* __restrict__ G1T,
                            float* __restrict__ G2T, float* __restrict__ df0b,
                            float* __restrict__ dzb, float* __restrict__ doutb) {
    int idx = blockIdx.x*256 + threadIdx.x;   // 1327104 total
    int b = idx & 31;
    int r = idx >> 5;
    if (r < 6144) {
        int t = r / 768, i = r % 768;
        G0T[idx] = coefs[b*48 + t*6 + 0] * xbarT[(size_t)i*32 + b];
    } else if (r < 12288) {
        int rr = r - 6144;
        int t = rr / 768, i = rr % 768;
        G1T[(size_t)rr*32 + b] = coefs[b*48 + t*6 + 2] * f0T[(size_t)i*32 + b];
    } else if (r < 36864) {
        int rr = r - 12288;
        int t = rr / 3072, i = rr % 3072;
        G2T[(size_t)rr*32 + b] = coefs[b*48 + t*6 + 4] * fT[(size_t)i*32 + b];
    } else if (r < 37632) {
        int n = r - 36864;
        float s = 0.f;
#pragma unroll
        for (int t = 0; t < 8; ++t) s += coefs[b*48 + t*6 + 1] * dbp[t*768 + n];
        df0b[(size_t)n*32 + b] = s;
    } else if (r < 40704) {
        int n = r - 37632;
        float s = 0.f;
#pragma unroll
        for (int t = 0; t < 8; ++t) s += coefs[b*48 + t*6 + 3] * db1[t*3072 + n];
        dzb[(size_t)n*32 + b] = s;
    } else if (r < 41472) {
        int n = r - 40704;
        float s = 0.f;
#pragma unroll
        for (int t = 0; t < 8; ++t) s += coefs[b*48 + t*6 + 5] * db2[t*768 + n];
        doutb[(size_t)n*32 + b] = s;
    }
}

extern "C" void kernel_launch(void* const* d_in, const int* in_sizes, int n_in,
                              void* d_out, int out_size, void* d_ws, size_t ws_size,
                              hipStream_t stream) {
    const float* x   = (const float*)d_in[0];
    const float* Wp  = (const float*)d_in[1];
    const float* bp  = (const float*)d_in[2];
    const float* W1  = (const float*)d_in[3];
    const float* b1  = (const float*)d_in[4];
    const float* W2  = (const float*)d_in[5];
    const float* b2  = (const float*)d_in[6];
    const float* dWp = (const float*)d_in[7];
    const float* dbp = (const float*)d_in[8];
    const float* dW1 = (const float*)d_in[9];
    const float* db1 = (const float*)d_in[10];
    const float* dW2 = (const float*)d_in[11];
    const float* db2 = (const float*)d_in[12];
    const float* mW1 = (const float*)d_in[13];
    const float* mb1 = (const float*)d_in[14];
    const float* mW2 = (const float*)d_in[15];
    const float* mb2 = (const float*)d_in[16];
    float* out = (float*)d_out;

    float* ws    = (float*)d_ws;
    float* part  = ws;                 // 344064
    float* xbarT = part  + 344064;     // 24576   [768,32]
    float* f0T   = xbarT + 24576;      // 24576
    float* zT    = f0T   + 24576;      // 98304
    float* fT    = zT    + 98304;      // 98304
    float* baseT = fT    + 98304;      // 24576
    float* coefs = baseT + 24576;      // 1536
    float* G0T   = coefs + 1536;       // 196608  [6144,32]
    float* G1T   = G0T   + 196608;     // 196608  [6144,32]
    float* G2T   = G1T   + 196608;     // 786432  [24576,32]
    float* df0b  = G2T   + 786432;     // 24576
    float* dzb   = df0b  + 24576;      // 98304
    float* doutb = dzb   + 98304;      // 24576
    float* dfT   = doutb + 24576;      // 98304
    float* df0T  = dfT   + 98304;      // 24576
    // partial arenas (reused across phases; no lifetime overlap)
    float* A1 = df0T + 24576;          // 3145728 : Pz (12), then Pdz (30 slices of 98304)
    float* A2 = A1 + 3145728;          // 3145728 : Pbase(48), then Pdout (120 slices of 24576)
    float* A3 = A2 + 3145728;          // 1179648 : Pf0 (12), then Pdf0 (48 slices of 24576)
    float* mv = A3 + 1179648;          // 6144    : MetaNet hidden v[32,192]
    // total ~9.6M floats = ~38.5 MB

    // 1) per-sample patch mean
    patch_partial_k<<<1344, 256, 0, stream>>>(x, part);
    patch_reduce_k<<<96, 256, 0, stream>>>(part, xbarT);

    // 2) base path
    gemm4_k<768, 16><<<dim3(12, 12), 256, 0, stream>>>(xbarT, Wp, A3);   // K=768,  12 slices
    reduce_bias_k<12><<<96, 256, 0, stream>>>(A3, bp, f0T, 24576);
    gemm4_k<3072, 16><<<dim3(48, 12), 256, 0, stream>>>(f0T, W1, A1);    // K=768,  12 slices
    reduce_zf_k<12><<<384, 256, 0, stream>>>(A1, b1, zT, fT);
    gemm4_k<768, 16><<<dim3(12, 48), 256, 0, stream>>>(fT, W2, A2);      // K=3072, 48 slices
    reduce_bias_k<48><<<96, 256, 0, stream>>>(A2, b2, baseT, 24576);

    // 3) MetaNet coefficients (parallelized: 192-block layer1 + 32-block layer2)
    metanet1_k<<<dim3(32, 6), 256, 0, stream>>>(baseT, mW1, mb1, mv);
    metanet2_k<<<32, 256, 0, stream>>>(mv, mW2, mb2, coefs);

    // 4) scaled A-operands + delta-bias inits
    build_all_k<<<5184, 256, 0, stream>>>(coefs, xbarT, f0T, fT, dbp, db1, db2,
                                          G0T, G1T, G2T, df0b, dzb, doutb);

    // 5) JVP chain
    gemm4_k<768, 32><<<dim3(12, 48), 256, 0, stream>>>(G0T, dWp, A3);    // K=6144, 48 slices
    reduce_arr_k<48><<<96, 256, 0, stream>>>(A3, df0b, df0T, 24576);
    gemm4_k<3072, 32><<<dim3(48, 6), 256, 0, stream>>>(df0T, W1, A1);    // K=768, slices 0..6
    gemm4_k<3072, 64><<<dim3(48, 24), 256, 0, stream>>>(G1T, dW1, A1 + (size_t)6*98304);  // K=6144, slices 6..30
    reduce_mask_k<30><<<384, 256, 0, stream>>>(A1, dzb, zT, dfT);
    gemm4_k<768, 32><<<dim3(12, 24), 256, 0, stream>>>(dfT, W2, A2);     // K=3072, slices 0..24
    gemm4_k<768, 64><<<dim3(12, 96), 256, 0, stream>>>(G2T, dW2, A2 + (size_t)24*24576); // K=24576, slices 24..120
    reduce_out_k<120><<<96, 256, 0, stream>>>(A2, doutb, baseT, out);
}